// Round 1
// baseline (1701.052 us; speedup 1.0000x reference)
//
#include <hip/hip_runtime.h>
#include <hip/hip_bf16.h>
#include <cstdint>

typedef short bf16x8 __attribute__((ext_vector_type(8)));
typedef float f32x4 __attribute__((ext_vector_type(4)));

__device__ __forceinline__ ushort f2bf(float x) {
  uint32_t u = __float_as_uint(x);
  u += 0x7FFFu + ((u >> 16) & 1u);
  return (ushort)(u >> 16);
}

// ---------------- conversions ----------------
__global__ __launch_bounds__(256) void k_f32_to_bf16(const float* __restrict__ in,
                                                     ushort* __restrict__ out, int n4) {
  int i = blockIdx.x * 256 + threadIdx.x;
  if (i >= n4) return;
  const float4 v = reinterpret_cast<const float4*>(in)[i];
  ushort4 o;
  o.x = f2bf(v.x); o.y = f2bf(v.y); o.z = f2bf(v.z); o.w = f2bf(v.w);
  reinterpret_cast<ushort4*>(out)[i] = o;
}

// W [K,Nc] row-major f32 -> Bt [Nc,K] bf16 (N-major, K contiguous)
__global__ __launch_bounds__(256) void k_convT(const float* __restrict__ W,
                                               ushort* __restrict__ Bt, int K, int Nc) {
  int i = blockIdx.x * 256 + threadIdx.x;
  if (i >= K * Nc) return;
  int nn = i / K, kk = i - nn * K;
  Bt[i] = f2bf(W[kk * Nc + nn]);
}

// ---------------- GEMM: C = relu?(A[M,256] * B[256,BNcols] + bias) ----------------
// A bf16 [M,256] row-major; Bt bf16 [Ncols,256] (transposed, K contig).
// BM=128, BK=64. 4 waves; wave grid WGR x WGC.
template<int BN, int WGR, int WGC, bool RELU, bool OUTBF16>
__global__ __launch_bounds__(256) void k_gemm(const ushort* __restrict__ A,
                                              const ushort* __restrict__ Bt,
                                              const float* __restrict__ bias,
                                              void* __restrict__ Cout, int M, int ldc) {
  constexpr int BM = 128, BK = 64, KTOT = 256;
  constexpr int WM = BM / WGR, WN = BN / WGC;
  constexpr int MR = WM / 16, NR = WN / 16;
  __shared__ ushort lA[BM * BK];
  __shared__ ushort lB[BN * BK];
  const int tid = threadIdx.x;
  const int w = tid >> 6, lane = tid & 63;
  const int wr = w / WGC, wc = w % WGC;
  const int bm = blockIdx.x * BM;
  const int bn = blockIdx.y * BN;
  f32x4 acc[MR][NR] = {};

  for (int ks = 0; ks < KTOT; ks += BK) {
    // stage A tile (BM x BK), 16B chunks, XOR-swizzled chunk index
    for (int c = tid; c < BM * 8; c += 256) {
      int r = c >> 3, ch = c & 7;
      int gr = bm + r;
      bf16x8 val = {};
      if (gr < M) val = *reinterpret_cast<const bf16x8*>(A + (size_t)gr * KTOT + ks + ch * 8);
      *reinterpret_cast<bf16x8*>(lA + r * BK + (ch ^ (r & 7)) * 8) = val;
    }
    // stage B tile (BN x BK)
    for (int c = tid; c < BN * 8; c += 256) {
      int r = c >> 3, ch = c & 7;
      bf16x8 val = *reinterpret_cast<const bf16x8*>(Bt + (size_t)(bn + r) * KTOT + ks + ch * 8);
      *reinterpret_cast<bf16x8*>(lB + r * BK + (ch ^ (r & 7)) * 8) = val;
    }
    __syncthreads();
    #pragma unroll
    for (int kk = 0; kk < 2; ++kk) {
      bf16x8 af[MR], bfr[NR];
      int kc = kk * 4 + (lane >> 4);  // 16B chunk index along K (k = kc*8)
      #pragma unroll
      for (int m = 0; m < MR; ++m) {
        int r = wr * WM + m * 16 + (lane & 15);
        af[m] = *reinterpret_cast<const bf16x8*>(lA + r * BK + (kc ^ (r & 7)) * 8);
      }
      #pragma unroll
      for (int n = 0; n < NR; ++n) {
        int r = wc * WN + n * 16 + (lane & 15);
        bfr[n] = *reinterpret_cast<const bf16x8*>(lB + r * BK + (kc ^ (r & 7)) * 8);
      }
      #pragma unroll
      for (int m = 0; m < MR; ++m)
        #pragma unroll
        for (int n = 0; n < NR; ++n)
          acc[m][n] = __builtin_amdgcn_mfma_f32_16x16x32_bf16(af[m], bfr[n], acc[m][n], 0, 0, 0);
    }
    __syncthreads();
  }
  // epilogue: C/D layout col=lane&15, row=(lane>>4)*4+j  [m89-verified]
  #pragma unroll
  for (int m = 0; m < MR; ++m) {
    #pragma unroll
    for (int n = 0; n < NR; ++n) {
      int col = bn + wc * WN + n * 16 + (lane & 15);
      float bv = bias[col];
      #pragma unroll
      for (int j = 0; j < 4; ++j) {
        int row = bm + wr * WM + m * 16 + (lane >> 4) * 4 + j;
        if (row < M) {
          float v = acc[m][n][j] + bv;
          if (RELU) v = fmaxf(v, 0.f);
          if (OUTBF16) ((ushort*)Cout)[(size_t)row * ldc + col] = f2bf(v);
          else        ((float*)Cout)[(size_t)row * ldc + col] = v;
        }
      }
    }
  }
}

// ---------------- graph prep ----------------
__global__ __launch_bounds__(256) void k_count(const int* __restrict__ dst, int* cnt, int E) {
  int e = blockIdx.x * 256 + threadIdx.x;
  if (e < E) atomicAdd(&cnt[dst[e]], 1);
}

__global__ __launch_bounds__(256) void k_scan_block(const int* __restrict__ cnt,
                                                    int* __restrict__ pre,
                                                    int* __restrict__ bsum, int n) {
  __shared__ int sh[256];
  int t = threadIdx.x, b = blockIdx.x;
  int base = b * 1024 + t * 4;
  int v0 = 0, v1 = 0, v2 = 0, v3 = 0;
  if (base + 0 < n) v0 = cnt[base + 0];
  if (base + 1 < n) v1 = cnt[base + 1];
  if (base + 2 < n) v2 = cnt[base + 2];
  if (base + 3 < n) v3 = cnt[base + 3];
  int s = v0 + v1 + v2 + v3;
  sh[t] = s;
  __syncthreads();
  for (int off = 1; off < 256; off <<= 1) {
    int x = (t >= off) ? sh[t - off] : 0;
    __syncthreads();
    sh[t] += x;
    __syncthreads();
  }
  if (t == 255) bsum[b] = sh[255];
  int p = sh[t] - s;  // exclusive prefix for this thread
  if (base + 0 < n) pre[base + 0] = p; p += v0;
  if (base + 1 < n) pre[base + 1] = p; p += v1;
  if (base + 2 < n) pre[base + 2] = p; p += v2;
  if (base + 3 < n) pre[base + 3] = p;
}

__global__ __launch_bounds__(256) void k_scan_bsum(int* bsum, int nb) {
  __shared__ int sh[256];
  int t = threadIdx.x;
  int v = (t < nb) ? bsum[t] : 0;
  sh[t] = v;
  __syncthreads();
  for (int off = 1; off < 256; off <<= 1) {
    int x = (t >= off) ? sh[t - off] : 0;
    __syncthreads();
    sh[t] += x;
    __syncthreads();
  }
  if (t < nb) bsum[t] = sh[t] - v;  // exclusive
}

__global__ __launch_bounds__(256) void k_scan_add(int* __restrict__ pre,
                                                  const int* __restrict__ bsum,
                                                  int n, int Etot) {
  int i = blockIdx.x * 256 + threadIdx.x;
  if (i < n) pre[i] += bsum[i >> 10];
  if (i == 0) pre[n] = Etot;
}

__global__ __launch_bounds__(256) void k_norm(const int* __restrict__ cnt,
                                              float* __restrict__ nrm, int n) {
  int v = blockIdx.x * 256 + threadIdx.x;
  if (v < n) nrm[v] = (cnt[v] > 0) ? rsqrtf((float)cnt[v]) : 0.f;
}

__global__ __launch_bounds__(256) void k_scatter(const int* __restrict__ src,
                                                 const int* __restrict__ dst,
                                                 const int* __restrict__ rp,
                                                 int* __restrict__ fill,
                                                 int* __restrict__ ss, int E) {
  int e = blockIdx.x * 256 + threadIdx.x;
  if (e < E) {
    int d = dst[e];
    int pos = rp[d] + atomicAdd(&fill[d], 1);
    ss[pos] = src[e];
  }
}

// ---------------- pooling init: x is in `out`; out <- sig(x.s)*x; hs0 <- x*norm ----------------
__global__ __launch_bounds__(256) void k_init(float* __restrict__ out,
                                              float* __restrict__ hs0,
                                              const float* __restrict__ nrm,
                                              const float* __restrict__ svec, int Nn) {
  int sub = threadIdx.x >> 5, lane = threadIdx.x & 31;
  int v = blockIdx.x * 8 + sub;
  if (v >= Nn) return;
  float x = out[v * 32 + lane];
  float p = x * svec[lane];
  #pragma unroll
  for (int m = 16; m >= 1; m >>= 1) p += __shfl_xor(p, m);
  float g = 1.f / (1.f + __expf(-p));
  hs0[v * 32 + lane] = x * nrm[v];
  out[v * 32 + lane] = g * x;
}

// ---------------- one propagation hop, pooling fused ----------------
// hs_in = h_prev * norm.  h2[v] = norm[v]*sum_{e in CSR[v]} hs_in[src_e]
// out[v] += sigmoid(h2.s)*h2 ; hs_out[v] = h2*norm[v]
__global__ __launch_bounds__(256) void k_prop(const float* __restrict__ hs_in,
                                              float* __restrict__ hs_out,
                                              float* __restrict__ outacc,
                                              const int* __restrict__ rp,
                                              const int* __restrict__ ss,
                                              const float* __restrict__ nrm,
                                              const float* __restrict__ svec, int Nn) {
  int sub = threadIdx.x >> 5, lane = threadIdx.x & 31;
  int v = blockIdx.x * 8 + sub;
  if (v >= Nn) return;
  int beg = rp[v], end = rp[v + 1];
  float acc = 0.f;
  for (int i = beg; i < end; ++i) {
    int u = ss[i];
    acc += hs_in[u * 32 + lane];
  }
  float nv = nrm[v];
  float h2 = acc * nv;
  float p = h2 * svec[lane];
  #pragma unroll
  for (int m = 16; m >= 1; m >>= 1) p += __shfl_xor(p, m);
  float g = 1.f / (1.f + __expf(-p));
  outacc[v * 32 + lane] += g * h2;
  hs_out[v * 32 + lane] = h2 * nv;
}

// ---------------- launch ----------------
extern "C" void kernel_launch(void* const* d_in, const int* in_sizes, int n_in,
                              void* d_out, int out_size, void* d_ws, size_t ws_size,
                              hipStream_t stream) {
  const float* feats = (const float*)d_in[0];
  const float* W1 = (const float*)d_in[1];
  const float* b1 = (const float*)d_in[2];
  const float* W2 = (const float*)d_in[3];
  const float* b2 = (const float*)d_in[4];
  const float* W3 = (const float*)d_in[5];
  const float* b3 = (const float*)d_in[6];
  const float* svec = (const float*)d_in[7];
  const int* src = (const int*)d_in[8];
  const int* dst = (const int*)d_in[9];

  const int DIN = 256, DH = 256, DOUT = 32, KHOP = 16;
  const int N = in_sizes[0] / DIN;
  const int E = in_sizes[8];

  char* w = (char*)d_ws;
  auto alloc = [&](size_t bytes) {
    char* p = w;
    w += (bytes + 255) & ~(size_t)255;
    return p;
  };
  ushort* featsb = (ushort*)alloc((size_t)N * DIN * 2);  // also reused as x2b
  ushort* x1b    = (ushort*)alloc((size_t)N * DH * 2);
  ushort* w1t = (ushort*)alloc((size_t)DIN * DH * 2);
  ushort* w2t = (ushort*)alloc((size_t)DH * DH * 2);
  ushort* w3t = (ushort*)alloc((size_t)DH * DOUT * 2);
  float* hsA = (float*)alloc((size_t)N * DOUT * 4);
  float* hsB = (float*)alloc((size_t)N * DOUT * 4);
  float* nrm = (float*)alloc((size_t)N * 4);
  int* cnt = (int*)alloc((size_t)N * 4);
  int* rp  = (int*)alloc((size_t)(N + 1) * 4);
  int* bsum = (int*)alloc(1024 * 4);
  int* ss  = (int*)alloc((size_t)E * 4);
  float* xout = (float*)d_out;

  // conversions
  k_f32_to_bf16<<<dim3((N * DIN / 4 + 255) / 256), 256, 0, stream>>>(feats, featsb, N * DIN / 4);
  k_convT<<<dim3((DIN * DH + 255) / 256), 256, 0, stream>>>(W1, w1t, DIN, DH);
  k_convT<<<dim3((DH * DH + 255) / 256), 256, 0, stream>>>(W2, w2t, DH, DH);
  k_convT<<<dim3((DH * DOUT + 255) / 256), 256, 0, stream>>>(W3, w3t, DH, DOUT);

  // graph prep: degree count -> row_ptr scan -> norm -> CSR scatter
  hipMemsetAsync(cnt, 0, (size_t)N * 4, stream);
  k_count<<<dim3((E + 255) / 256), 256, 0, stream>>>(dst, cnt, E);
  int nb = (N + 1023) / 1024;
  k_scan_block<<<dim3(nb), 256, 0, stream>>>(cnt, rp, bsum, N);
  k_scan_bsum<<<dim3(1), 256, 0, stream>>>(bsum, nb);
  k_scan_add<<<dim3((N + 255) / 256), 256, 0, stream>>>(rp, bsum, N, E);
  k_norm<<<dim3((N + 255) / 256), 256, 0, stream>>>(cnt, nrm, N);
  hipMemsetAsync(cnt, 0, (size_t)N * 4, stream);  // reuse as fill counters
  k_scatter<<<dim3((E + 255) / 256), 256, 0, stream>>>(src, dst, rp, cnt, ss, E);

  // MLP (bf16 MFMA, fp32 accum)
  dim3 g1((N + 127) / 128, DH / 128);
  k_gemm<128, 2, 2, true, true><<<g1, 256, 0, stream>>>(featsb, w1t, b1, x1b, N, DH);
  k_gemm<128, 2, 2, true, true><<<g1, 256, 0, stream>>>(x1b, w2t, b2, featsb, N, DH);
  dim3 g3((N + 127) / 128, 1);
  k_gemm<32, 4, 1, false, false><<<g3, 256, 0, stream>>>(featsb, w3t, b3, xout, N, DOUT);

  // pooling init (hop 0) + 16 propagation hops with fused gated pooling
  k_init<<<dim3((N + 7) / 8), 256, 0, stream>>>(xout, hsA, nrm, svec, N);
  float* hin = hsA;
  float* hout = hsB;
  for (int h = 0; h < KHOP; ++h) {
    k_prop<<<dim3((N + 7) / 8), 256, 0, stream>>>(hin, hout, xout, rp, ss, nrm, svec, N);
    float* t = hin; hin = hout; hout = t;
  }
}

// Round 2
// 1046.411 us; speedup vs baseline: 1.6256x; 1.6256x over previous
//
#include <hip/hip_runtime.h>
#include <hip/hip_bf16.h>
#include <cstdint>

typedef short bf16x8 __attribute__((ext_vector_type(8)));
typedef float f32x4 __attribute__((ext_vector_type(4)));

__device__ __forceinline__ ushort f2bf(float x) {
  uint32_t u = __float_as_uint(x);
  u += 0x7FFFu + ((u >> 16) & 1u);
  return (ushort)(u >> 16);
}

// ---------------- conversions ----------------
__global__ __launch_bounds__(256) void k_f32_to_bf16(const float* __restrict__ in,
                                                     ushort* __restrict__ out, int n4) {
  int i = blockIdx.x * 256 + threadIdx.x;
  if (i >= n4) return;
  const float4 v = reinterpret_cast<const float4*>(in)[i];
  ushort4 o;
  o.x = f2bf(v.x); o.y = f2bf(v.y); o.z = f2bf(v.z); o.w = f2bf(v.w);
  reinterpret_cast<ushort4*>(out)[i] = o;
}

// W [K,Nc] row-major f32 -> Bt [Nc,K] bf16 (N-major, K contiguous)
__global__ __launch_bounds__(256) void k_convT(const float* __restrict__ W,
                                               ushort* __restrict__ Bt, int K, int Nc) {
  int i = blockIdx.x * 256 + threadIdx.x;
  if (i >= K * Nc) return;
  int nn = i / K, kk = i - nn * K;
  Bt[i] = f2bf(W[kk * Nc + nn]);
}

// ---------------- GEMM: C = relu?(A[M,256] * B[256,BNcols] + bias) ----------------
template<int BN, int WGR, int WGC, bool RELU, bool OUTBF16>
__global__ __launch_bounds__(256) void k_gemm(const ushort* __restrict__ A,
                                              const ushort* __restrict__ Bt,
                                              const float* __restrict__ bias,
                                              void* __restrict__ Cout, int M, int ldc) {
  constexpr int BM = 128, BK = 64, KTOT = 256;
  constexpr int WM = BM / WGR, WN = BN / WGC;
  constexpr int MR = WM / 16, NR = WN / 16;
  __shared__ ushort lA[BM * BK];
  __shared__ ushort lB[BN * BK];
  const int tid = threadIdx.x;
  const int w = tid >> 6, lane = tid & 63;
  const int wr = w / WGC, wc = w % WGC;
  const int bm = blockIdx.x * BM;
  const int bn = blockIdx.y * BN;
  f32x4 acc[MR][NR] = {};

  for (int ks = 0; ks < KTOT; ks += BK) {
    for (int c = tid; c < BM * 8; c += 256) {
      int r = c >> 3, ch = c & 7;
      int gr = bm + r;
      bf16x8 val = {};
      if (gr < M) val = *reinterpret_cast<const bf16x8*>(A + (size_t)gr * KTOT + ks + ch * 8);
      *reinterpret_cast<bf16x8*>(lA + r * BK + (ch ^ (r & 7)) * 8) = val;
    }
    for (int c = tid; c < BN * 8; c += 256) {
      int r = c >> 3, ch = c & 7;
      bf16x8 val = *reinterpret_cast<const bf16x8*>(Bt + (size_t)(bn + r) * KTOT + ks + ch * 8);
      *reinterpret_cast<bf16x8*>(lB + r * BK + (ch ^ (r & 7)) * 8) = val;
    }
    __syncthreads();
    #pragma unroll
    for (int kk = 0; kk < 2; ++kk) {
      bf16x8 af[MR], bfr[NR];
      int kc = kk * 4 + (lane >> 4);
      #pragma unroll
      for (int m = 0; m < MR; ++m) {
        int r = wr * WM + m * 16 + (lane & 15);
        af[m] = *reinterpret_cast<const bf16x8*>(lA + r * BK + (kc ^ (r & 7)) * 8);
      }
      #pragma unroll
      for (int n = 0; n < NR; ++n) {
        int r = wc * WN + n * 16 + (lane & 15);
        bfr[n] = *reinterpret_cast<const bf16x8*>(lB + r * BK + (kc ^ (r & 7)) * 8);
      }
      #pragma unroll
      for (int m = 0; m < MR; ++m)
        #pragma unroll
        for (int n = 0; n < NR; ++n)
          acc[m][n] = __builtin_amdgcn_mfma_f32_16x16x32_bf16(af[m], bfr[n], acc[m][n], 0, 0, 0);
    }
    __syncthreads();
  }
  #pragma unroll
  for (int m = 0; m < MR; ++m) {
    #pragma unroll
    for (int n = 0; n < NR; ++n) {
      int col = bn + wc * WN + n * 16 + (lane & 15);
      float bv = bias[col];
      #pragma unroll
      for (int j = 0; j < 4; ++j) {
        int row = bm + wr * WM + m * 16 + (lane >> 4) * 4 + j;
        if (row < M) {
          float v = acc[m][n][j] + bv;
          if (RELU) v = fmaxf(v, 0.f);
          if (OUTBF16) ((ushort*)Cout)[(size_t)row * ldc + col] = f2bf(v);
          else        ((float*)Cout)[(size_t)row * ldc + col] = v;
        }
      }
    }
  }
}

// ---------------- graph prep ----------------
__global__ __launch_bounds__(256) void k_count(const int* __restrict__ dst, int* cnt, int E) {
  int e = blockIdx.x * 256 + threadIdx.x;
  if (e < E) atomicAdd(&cnt[dst[e]], 1);
}

__global__ __launch_bounds__(256) void k_scan_block(const int* __restrict__ cnt,
                                                    int* __restrict__ pre,
                                                    int* __restrict__ bsum, int n) {
  __shared__ int sh[256];
  int t = threadIdx.x, b = blockIdx.x;
  int base = b * 1024 + t * 4;
  int v0 = 0, v1 = 0, v2 = 0, v3 = 0;
  if (base + 0 < n) v0 = cnt[base + 0];
  if (base + 1 < n) v1 = cnt[base + 1];
  if (base + 2 < n) v2 = cnt[base + 2];
  if (base + 3 < n) v3 = cnt[base + 3];
  int s = v0 + v1 + v2 + v3;
  sh[t] = s;
  __syncthreads();
  for (int off = 1; off < 256; off <<= 1) {
    int x = (t >= off) ? sh[t - off] : 0;
    __syncthreads();
    sh[t] += x;
    __syncthreads();
  }
  if (t == 255) bsum[b] = sh[255];
  int p = sh[t] - s;
  if (base + 0 < n) pre[base + 0] = p; p += v0;
  if (base + 1 < n) pre[base + 1] = p; p += v1;
  if (base + 2 < n) pre[base + 2] = p; p += v2;
  if (base + 3 < n) pre[base + 3] = p;
}

__global__ __launch_bounds__(256) void k_scan_bsum(int* bsum, int nb) {
  __shared__ int sh[256];
  int t = threadIdx.x;
  int v = (t < nb) ? bsum[t] : 0;
  sh[t] = v;
  __syncthreads();
  for (int off = 1; off < 256; off <<= 1) {
    int x = (t >= off) ? sh[t - off] : 0;
    __syncthreads();
    sh[t] += x;
    __syncthreads();
  }
  if (t < nb) bsum[t] = sh[t] - v;
}

__global__ __launch_bounds__(256) void k_scan_add(int* __restrict__ pre,
                                                  const int* __restrict__ bsum,
                                                  int n, int Etot) {
  int i = blockIdx.x * 256 + threadIdx.x;
  if (i < n) pre[i] += bsum[i >> 10];
  if (i == 0) pre[n] = Etot;
}

__global__ __launch_bounds__(256) void k_norm(const int* __restrict__ cnt,
                                              float* __restrict__ nrm, int n) {
  int v = blockIdx.x * 256 + threadIdx.x;
  if (v < n) nrm[v] = (cnt[v] > 0) ? rsqrtf((float)cnt[v]) : 0.f;
}

__global__ __launch_bounds__(256) void k_scatter(const int* __restrict__ src,
                                                 const int* __restrict__ dst,
                                                 const int* __restrict__ rp,
                                                 int* __restrict__ fill,
                                                 int* __restrict__ ss, int E) {
  int e = blockIdx.x * 256 + threadIdx.x;
  if (e < E) {
    int d = dst[e];
    int pos = rp[d] + atomicAdd(&fill[d], 1);
    ss[pos] = src[e];
  }
}

// ---------------- pooling init ----------------
__global__ __launch_bounds__(256) void k_init(float* __restrict__ out,
                                              float* __restrict__ hs0,
                                              const float* __restrict__ nrm,
                                              const float* __restrict__ svec, int Nn) {
  int sub = threadIdx.x >> 5, lane = threadIdx.x & 31;
  int v = blockIdx.x * 8 + sub;
  if (v >= Nn) return;
  float x = out[v * 32 + lane];
  float p = x * svec[lane];
  #pragma unroll
  for (int m = 16; m >= 1; m >>= 1) p += __shfl_xor(p, m);
  float g = 1.f / (1.f + __expf(-p));
  hs0[v * 32 + lane] = x * nrm[v];
  out[v * 32 + lane] = g * x;
}

// ---------------- one propagation hop, pooling fused ----------------
// One node per 64-lane wave. lane = e8*8 + d8: 8 edge slots x 8 float4 dim-chunks.
// 8 edges (8x128B) in flight per wave-step instead of 1.
__global__ __launch_bounds__(256) void k_prop(const float* __restrict__ hs_in,
                                              float* __restrict__ hs_out,
                                              float* __restrict__ outacc,
                                              const int* __restrict__ rp,
                                              const int* __restrict__ ss,
                                              const float* __restrict__ nrm,
                                              const float* __restrict__ svec, int Nn) {
  const int wave = threadIdx.x >> 6;
  const int lane = threadIdx.x & 63;
  const int e8 = lane >> 3;   // edge slot
  const int d8 = lane & 7;    // float4 dim chunk
  const int v = blockIdx.x * 4 + wave;
  if (v >= Nn) return;
  const int beg = rp[v], end = rp[v + 1];
  float4 acc = {0.f, 0.f, 0.f, 0.f};
  for (int i = beg + e8; i < end; i += 8) {
    int u = ss[i];
    const float4 hv = *reinterpret_cast<const float4*>(hs_in + (size_t)u * 32 + d8 * 4);
    acc.x += hv.x; acc.y += hv.y; acc.z += hv.z; acc.w += hv.w;
  }
  // reduce across the 8 edge slots (lane bits 3,4,5)
  #pragma unroll
  for (int m = 8; m <= 32; m <<= 1) {
    acc.x += __shfl_xor(acc.x, m);
    acc.y += __shfl_xor(acc.y, m);
    acc.z += __shfl_xor(acc.z, m);
    acc.w += __shfl_xor(acc.w, m);
  }
  const float nv = nrm[v];
  float4 h2 = {acc.x * nv, acc.y * nv, acc.z * nv, acc.w * nv};
  const float4 sv = *reinterpret_cast<const float4*>(svec + d8 * 4);
  float p = h2.x * sv.x + h2.y * sv.y + h2.z * sv.z + h2.w * sv.w;
  #pragma unroll
  for (int m = 1; m <= 4; m <<= 1) p += __shfl_xor(p, m);
  const float g = 1.f / (1.f + __expf(-p));
  if (e8 == 0) {
    float4 hn = {h2.x * nv, h2.y * nv, h2.z * nv, h2.w * nv};
    *reinterpret_cast<float4*>(hs_out + (size_t)v * 32 + d8 * 4) = hn;
    float4* oa = reinterpret_cast<float4*>(outacc + (size_t)v * 32 + d8 * 4);
    float4 o = *oa;
    o.x += g * h2.x; o.y += g * h2.y; o.z += g * h2.z; o.w += g * h2.w;
    *oa = o;
  }
}

// ---------------- launch ----------------
extern "C" void kernel_launch(void* const* d_in, const int* in_sizes, int n_in,
                              void* d_out, int out_size, void* d_ws, size_t ws_size,
                              hipStream_t stream) {
  const float* feats = (const float*)d_in[0];
  const float* W1 = (const float*)d_in[1];
  const float* b1 = (const float*)d_in[2];
  const float* W2 = (const float*)d_in[3];
  const float* b2 = (const float*)d_in[4];
  const float* W3 = (const float*)d_in[5];
  const float* b3 = (const float*)d_in[6];
  const float* svec = (const float*)d_in[7];
  const int* src = (const int*)d_in[8];
  const int* dst = (const int*)d_in[9];

  const int DIN = 256, DH = 256, DOUT = 32, KHOP = 16;
  const int N = in_sizes[0] / DIN;
  const int E = in_sizes[8];

  char* w = (char*)d_ws;
  auto alloc = [&](size_t bytes) {
    char* p = w;
    w += (bytes + 255) & ~(size_t)255;
    return p;
  };
  ushort* featsb = (ushort*)alloc((size_t)N * DIN * 2);
  ushort* x1b    = (ushort*)alloc((size_t)N * DH * 2);
  ushort* w1t = (ushort*)alloc((size_t)DIN * DH * 2);
  ushort* w2t = (ushort*)alloc((size_t)DH * DH * 2);
  ushort* w3t = (ushort*)alloc((size_t)DH * DOUT * 2);
  float* hsA = (float*)alloc((size_t)N * DOUT * 4);
  float* hsB = (float*)alloc((size_t)N * DOUT * 4);
  float* nrm = (float*)alloc((size_t)N * 4);
  int* cnt = (int*)alloc((size_t)N * 4);
  int* rp  = (int*)alloc((size_t)(N + 1) * 4);
  int* bsum = (int*)alloc(1024 * 4);
  int* ss  = (int*)alloc((size_t)E * 4);
  float* xout = (float*)d_out;

  // conversions
  k_f32_to_bf16<<<dim3((N * DIN / 4 + 255) / 256), 256, 0, stream>>>(feats, featsb, N * DIN / 4);
  k_convT<<<dim3((DIN * DH + 255) / 256), 256, 0, stream>>>(W1, w1t, DIN, DH);
  k_convT<<<dim3((DH * DH + 255) / 256), 256, 0, stream>>>(W2, w2t, DH, DH);
  k_convT<<<dim3((DH * DOUT + 255) / 256), 256, 0, stream>>>(W3, w3t, DH, DOUT);

  // graph prep
  hipMemsetAsync(cnt, 0, (size_t)N * 4, stream);
  k_count<<<dim3((E + 255) / 256), 256, 0, stream>>>(dst, cnt, E);
  int nb = (N + 1023) / 1024;
  k_scan_block<<<dim3(nb), 256, 0, stream>>>(cnt, rp, bsum, N);
  k_scan_bsum<<<dim3(1), 256, 0, stream>>>(bsum, nb);
  k_scan_add<<<dim3((N + 255) / 256), 256, 0, stream>>>(rp, bsum, N, E);
  k_norm<<<dim3((N + 255) / 256), 256, 0, stream>>>(cnt, nrm, N);
  hipMemsetAsync(cnt, 0, (size_t)N * 4, stream);
  k_scatter<<<dim3((E + 255) / 256), 256, 0, stream>>>(src, dst, rp, cnt, ss, E);

  // MLP (bf16 MFMA, fp32 accum)
  dim3 g1((N + 127) / 128, DH / 128);
  k_gemm<128, 2, 2, true, true><<<g1, 256, 0, stream>>>(featsb, w1t, b1, x1b, N, DH);
  k_gemm<128, 2, 2, true, true><<<g1, 256, 0, stream>>>(x1b, w2t, b2, featsb, N, DH);
  dim3 g3((N + 127) / 128, 1);
  k_gemm<32, 4, 1, false, false><<<g3, 256, 0, stream>>>(featsb, w3t, b3, xout, N, DOUT);

  // pooling init + 16 hops
  k_init<<<dim3((N + 7) / 8), 256, 0, stream>>>(xout, hsA, nrm, svec, N);
  float* hin = hsA;
  float* hout = hsB;
  for (int h = 0; h < KHOP; ++h) {
    k_prop<<<dim3((N + 3) / 4), 256, 0, stream>>>(hin, hout, xout, rp, ss, nrm, svec, N);
    float* t = hin; hin = hout; hout = t;
  }
}

// Round 3
// 1009.306 us; speedup vs baseline: 1.6854x; 1.0368x over previous
//
#include <hip/hip_runtime.h>
#include <hip/hip_bf16.h>
#include <cstdint>

typedef short bf16x8 __attribute__((ext_vector_type(8)));
typedef float f32x4 __attribute__((ext_vector_type(4)));

__device__ __forceinline__ ushort f2bf(float x) {
  uint32_t u = __float_as_uint(x);
  u += 0x7FFFu + ((u >> 16) & 1u);
  return (ushort)(u >> 16);
}
__device__ __forceinline__ float bf2f(ushort b) {
  return __uint_as_float((uint32_t)b << 16);
}

// ---------------- conversions ----------------
__global__ __launch_bounds__(256) void k_f32_to_bf16(const float* __restrict__ in,
                                                     ushort* __restrict__ out, int n4) {
  int i = blockIdx.x * 256 + threadIdx.x;
  if (i >= n4) return;
  const float4 v = reinterpret_cast<const float4*>(in)[i];
  ushort4 o;
  o.x = f2bf(v.x); o.y = f2bf(v.y); o.z = f2bf(v.z); o.w = f2bf(v.w);
  reinterpret_cast<ushort4*>(out)[i] = o;
}

// W [K,Nc] row-major f32 -> Bt [Nc,K] bf16 (N-major, K contiguous)
__global__ __launch_bounds__(256) void k_convT(const float* __restrict__ W,
                                               ushort* __restrict__ Bt, int K, int Nc) {
  int i = blockIdx.x * 256 + threadIdx.x;
  if (i >= K * Nc) return;
  int nn = i / K, kk = i - nn * K;
  Bt[i] = f2bf(W[kk * Nc + nn]);
}

// ---------------- GEMM: C = relu?(A[M,256] * B[256,BNcols] + bias) ----------------
template<int BN, int WGR, int WGC, bool RELU, bool OUTBF16>
__global__ __launch_bounds__(256) void k_gemm(const ushort* __restrict__ A,
                                              const ushort* __restrict__ Bt,
                                              const float* __restrict__ bias,
                                              void* __restrict__ Cout, int M, int ldc) {
  constexpr int BM = 128, BK = 64, KTOT = 256;
  constexpr int WM = BM / WGR, WN = BN / WGC;
  constexpr int MR = WM / 16, NR = WN / 16;
  __shared__ ushort lA[BM * BK];
  __shared__ ushort lB[BN * BK];
  const int tid = threadIdx.x;
  const int w = tid >> 6, lane = tid & 63;
  const int wr = w / WGC, wc = w % WGC;
  const int bm = blockIdx.x * BM;
  const int bn = blockIdx.y * BN;
  f32x4 acc[MR][NR] = {};

  for (int ks = 0; ks < KTOT; ks += BK) {
    for (int c = tid; c < BM * 8; c += 256) {
      int r = c >> 3, ch = c & 7;
      int gr = bm + r;
      bf16x8 val = {};
      if (gr < M) val = *reinterpret_cast<const bf16x8*>(A + (size_t)gr * KTOT + ks + ch * 8);
      *reinterpret_cast<bf16x8*>(lA + r * BK + (ch ^ (r & 7)) * 8) = val;
    }
    for (int c = tid; c < BN * 8; c += 256) {
      int r = c >> 3, ch = c & 7;
      bf16x8 val = *reinterpret_cast<const bf16x8*>(Bt + (size_t)(bn + r) * KTOT + ks + ch * 8);
      *reinterpret_cast<bf16x8*>(lB + r * BK + (ch ^ (r & 7)) * 8) = val;
    }
    __syncthreads();
    #pragma unroll
    for (int kk = 0; kk < 2; ++kk) {
      bf16x8 af[MR], bfr[NR];
      int kc = kk * 4 + (lane >> 4);
      #pragma unroll
      for (int m = 0; m < MR; ++m) {
        int r = wr * WM + m * 16 + (lane & 15);
        af[m] = *reinterpret_cast<const bf16x8*>(lA + r * BK + (kc ^ (r & 7)) * 8);
      }
      #pragma unroll
      for (int n = 0; n < NR; ++n) {
        int r = wc * WN + n * 16 + (lane & 15);
        bfr[n] = *reinterpret_cast<const bf16x8*>(lB + r * BK + (kc ^ (r & 7)) * 8);
      }
      #pragma unroll
      for (int m = 0; m < MR; ++m)
        #pragma unroll
        for (int n = 0; n < NR; ++n)
          acc[m][n] = __builtin_amdgcn_mfma_f32_16x16x32_bf16(af[m], bfr[n], acc[m][n], 0, 0, 0);
    }
    __syncthreads();
  }
  #pragma unroll
  for (int m = 0; m < MR; ++m) {
    #pragma unroll
    for (int n = 0; n < NR; ++n) {
      int col = bn + wc * WN + n * 16 + (lane & 15);
      float bv = bias[col];
      #pragma unroll
      for (int j = 0; j < 4; ++j) {
        int row = bm + wr * WM + m * 16 + (lane >> 4) * 4 + j;
        if (row < M) {
          float v = acc[m][n][j] + bv;
          if (RELU) v = fmaxf(v, 0.f);
          if (OUTBF16) ((ushort*)Cout)[(size_t)row * ldc + col] = f2bf(v);
          else        ((float*)Cout)[(size_t)row * ldc + col] = v;
        }
      }
    }
  }
}

// ---------------- graph prep ----------------
__global__ __launch_bounds__(256) void k_count(const int* __restrict__ dst, int* cnt, int E) {
  int e = blockIdx.x * 256 + threadIdx.x;
  if (e < E) atomicAdd(&cnt[dst[e]], 1);
}

__global__ __launch_bounds__(256) void k_scan_block(const int* __restrict__ cnt,
                                                    int* __restrict__ pre,
                                                    int* __restrict__ bsum, int n) {
  __shared__ int sh[256];
  int t = threadIdx.x, b = blockIdx.x;
  int base = b * 1024 + t * 4;
  int v0 = 0, v1 = 0, v2 = 0, v3 = 0;
  if (base + 0 < n) v0 = cnt[base + 0];
  if (base + 1 < n) v1 = cnt[base + 1];
  if (base + 2 < n) v2 = cnt[base + 2];
  if (base + 3 < n) v3 = cnt[base + 3];
  int s = v0 + v1 + v2 + v3;
  sh[t] = s;
  __syncthreads();
  for (int off = 1; off < 256; off <<= 1) {
    int x = (t >= off) ? sh[t - off] : 0;
    __syncthreads();
    sh[t] += x;
    __syncthreads();
  }
  if (t == 255) bsum[b] = sh[255];
  int p = sh[t] - s;
  if (base + 0 < n) pre[base + 0] = p; p += v0;
  if (base + 1 < n) pre[base + 1] = p; p += v1;
  if (base + 2 < n) pre[base + 2] = p; p += v2;
  if (base + 3 < n) pre[base + 3] = p;
}

__global__ __launch_bounds__(256) void k_scan_bsum(int* bsum, int nb) {
  __shared__ int sh[256];
  int t = threadIdx.x;
  int v = (t < nb) ? bsum[t] : 0;
  sh[t] = v;
  __syncthreads();
  for (int off = 1; off < 256; off <<= 1) {
    int x = (t >= off) ? sh[t - off] : 0;
    __syncthreads();
    sh[t] += x;
    __syncthreads();
  }
  if (t < nb) bsum[t] = sh[t] - v;
}

__global__ __launch_bounds__(256) void k_scan_add(int* __restrict__ pre,
                                                  const int* __restrict__ bsum,
                                                  int n, int Etot) {
  int i = blockIdx.x * 256 + threadIdx.x;
  if (i < n) pre[i] += bsum[i >> 10];
  if (i == 0) pre[n] = Etot;
}

__global__ __launch_bounds__(256) void k_norm(const int* __restrict__ cnt,
                                              float* __restrict__ nrm, int n) {
  int v = blockIdx.x * 256 + threadIdx.x;
  if (v < n) nrm[v] = (cnt[v] > 0) ? rsqrtf((float)cnt[v]) : 0.f;
}

// ---------------- two-level counting-sort CSR build ----------------
// Level 1: bucket edges by dst>>8 into bucket-contiguous pair regions (sequential
// fill per bucket -> full-line writes). CHUNK=4096 edges per block, LDS-aggregated
// global reservations.
#define BSHIFT 8
#define NBMAX 512
__global__ __launch_bounds__(256) void k_bucket_scatter(const int* __restrict__ src,
                                                        const int* __restrict__ dst,
                                                        const int* __restrict__ rp,
                                                        int* __restrict__ gfill,
                                                        int2* __restrict__ tmp,
                                                        int E, int nbuck, int Nn) {
  __shared__ int lhist[NBMAX];
  __shared__ int lbase[NBMAX];
  const int t = threadIdx.x;
  const int base = blockIdx.x * 4096;
  for (int i = t; i < NBMAX; i += 256) lhist[i] = 0;
  __syncthreads();
  int myd[16];
  #pragma unroll
  for (int j = 0; j < 16; ++j) {
    int e = base + t + j * 256;
    myd[j] = (e < E) ? dst[e] : -1;
    if (myd[j] >= 0) atomicAdd(&lhist[myd[j] >> BSHIFT], 1);
  }
  __syncthreads();
  for (int i = t; i < nbuck; i += 256) {
    int c = lhist[i];
    lbase[i] = (c > 0) ? atomicAdd(&gfill[i], c) : 0;
    lhist[i] = 0;
  }
  __syncthreads();
  #pragma unroll
  for (int j = 0; j < 16; ++j) {
    int e = base + t + j * 256;
    if (myd[j] >= 0) {
      int b = myd[j] >> BSHIFT;
      int r = atomicAdd(&lhist[b], 1);
      int pos = rp[b << BSHIFT] + lbase[b] + r;
      tmp[pos] = make_int2(src[e], myd[j]);
    }
  }
}

// Level 2: one workgroup per bucket; finalize CSR order via LDS fill counters.
// Writes land in the bucket's contiguous CSR range -> L2-local, no amplification.
__global__ __launch_bounds__(256) void k_bucket_sort(const int2* __restrict__ tmp,
                                                     const int* __restrict__ rp,
                                                     int* __restrict__ ss, int Nn) {
  __shared__ int lfill[1 << BSHIFT];
  const int t = threadIdx.x;
  const int node0 = blockIdx.x << BSHIFT;
  const int node1 = min(node0 + (1 << BSHIFT), Nn);
  for (int i = t; i < (1 << BSHIFT); i += 256) lfill[i] = 0;
  __syncthreads();
  const int beg = rp[node0], end = rp[node1];
  for (int i = beg + t; i < end; i += 256) {
    int2 e = tmp[i];
    int r = atomicAdd(&lfill[e.y - node0], 1);
    ss[rp[e.y] + r] = e.x;
  }
}

// ---------------- pooling init ----------------
__global__ __launch_bounds__(256) void k_init(float* __restrict__ out,
                                              ushort* __restrict__ hs0,
                                              const float* __restrict__ nrm,
                                              const float* __restrict__ svec, int Nn) {
  int sub = threadIdx.x >> 5, lane = threadIdx.x & 31;
  int v = blockIdx.x * 8 + sub;
  if (v >= Nn) return;
  float x = out[v * 32 + lane];
  float p = x * svec[lane];
  #pragma unroll
  for (int m = 16; m >= 1; m >>= 1) p += __shfl_xor(p, m);
  float g = 1.f / (1.f + __expf(-p));
  hs0[v * 32 + lane] = f2bf(x * nrm[v]);
  out[v * 32 + lane] = g * x;
}

// ---------------- one propagation hop, pooling fused ----------------
// One node per 64-lane wave; lane = e8*8 + d8. hs rows are bf16 (64B).
__global__ __launch_bounds__(256) void k_prop(const ushort* __restrict__ hs_in,
                                              ushort* __restrict__ hs_out,
                                              float* __restrict__ outacc,
                                              const int* __restrict__ rp,
                                              const int* __restrict__ ss,
                                              const float* __restrict__ nrm,
                                              const float* __restrict__ svec, int Nn) {
  const int wave = threadIdx.x >> 6;
  const int lane = threadIdx.x & 63;
  const int e8 = lane >> 3;   // edge slot
  const int d8 = lane & 7;    // 4-dim chunk
  const int v = blockIdx.x * 4 + wave;
  if (v >= Nn) return;
  const int beg = rp[v], end = rp[v + 1];
  float4 acc = {0.f, 0.f, 0.f, 0.f};
  for (int i = beg + e8; i < end; i += 8) {
    int u = ss[i];
    ushort4 hv = *reinterpret_cast<const ushort4*>(hs_in + (size_t)u * 32 + d8 * 4);
    acc.x += bf2f(hv.x); acc.y += bf2f(hv.y); acc.z += bf2f(hv.z); acc.w += bf2f(hv.w);
  }
  #pragma unroll
  for (int m = 8; m <= 32; m <<= 1) {
    acc.x += __shfl_xor(acc.x, m);
    acc.y += __shfl_xor(acc.y, m);
    acc.z += __shfl_xor(acc.z, m);
    acc.w += __shfl_xor(acc.w, m);
  }
  const float nv = nrm[v];
  float4 h2 = {acc.x * nv, acc.y * nv, acc.z * nv, acc.w * nv};
  const float4 sv = *reinterpret_cast<const float4*>(svec + d8 * 4);
  float p = h2.x * sv.x + h2.y * sv.y + h2.z * sv.z + h2.w * sv.w;
  #pragma unroll
  for (int m = 1; m <= 4; m <<= 1) p += __shfl_xor(p, m);
  const float g = 1.f / (1.f + __expf(-p));
  if (e8 == 0) {
    ushort4 hn;
    hn.x = f2bf(h2.x * nv); hn.y = f2bf(h2.y * nv);
    hn.z = f2bf(h2.z * nv); hn.w = f2bf(h2.w * nv);
    *reinterpret_cast<ushort4*>(hs_out + (size_t)v * 32 + d8 * 4) = hn;
    float4* oa = reinterpret_cast<float4*>(outacc + (size_t)v * 32 + d8 * 4);
    float4 o = *oa;
    o.x += g * h2.x; o.y += g * h2.y; o.z += g * h2.z; o.w += g * h2.w;
    *oa = o;
  }
}

// ---------------- launch ----------------
extern "C" void kernel_launch(void* const* d_in, const int* in_sizes, int n_in,
                              void* d_out, int out_size, void* d_ws, size_t ws_size,
                              hipStream_t stream) {
  const float* feats = (const float*)d_in[0];
  const float* W1 = (const float*)d_in[1];
  const float* b1 = (const float*)d_in[2];
  const float* W2 = (const float*)d_in[3];
  const float* b2 = (const float*)d_in[4];
  const float* W3 = (const float*)d_in[5];
  const float* b3 = (const float*)d_in[6];
  const float* svec = (const float*)d_in[7];
  const int* src = (const int*)d_in[8];
  const int* dst = (const int*)d_in[9];

  const int DIN = 256, DH = 256, DOUT = 32, KHOP = 16;
  const int N = in_sizes[0] / DIN;
  const int E = in_sizes[8];
  const int nbuck = (N + (1 << BSHIFT) - 1) >> BSHIFT;

  char* w = (char*)d_ws;
  auto alloc = [&](size_t bytes) {
    char* p = w;
    w += (bytes + 255) & ~(size_t)255;
    return p;
  };
  ushort* featsb = (ushort*)alloc((size_t)N * DIN * 2);
  ushort* x1b    = (ushort*)alloc((size_t)N * DH * 2);
  ushort* w1t = (ushort*)alloc((size_t)DIN * DH * 2);
  ushort* w2t = (ushort*)alloc((size_t)DH * DH * 2);
  ushort* w3t = (ushort*)alloc((size_t)DH * DOUT * 2);
  ushort* hsA = (ushort*)alloc((size_t)N * DOUT * 2);
  ushort* hsB = (ushort*)alloc((size_t)N * DOUT * 2);
  float* nrm = (float*)alloc((size_t)N * 4);
  int* cnt = (int*)alloc((size_t)N * 4);
  int* rp  = (int*)alloc((size_t)(N + 1) * 4);
  int* bsum = (int*)alloc(1024 * 4);
  int* gfill = (int*)alloc((size_t)NBMAX * 4);
  int* ss  = (int*)alloc((size_t)E * 4);
  int2* tmp = (int2*)alloc((size_t)E * 8);
  float* xout = (float*)d_out;

  // conversions
  k_f32_to_bf16<<<dim3((N * DIN / 4 + 255) / 256), 256, 0, stream>>>(feats, featsb, N * DIN / 4);
  k_convT<<<dim3((DIN * DH + 255) / 256), 256, 0, stream>>>(W1, w1t, DIN, DH);
  k_convT<<<dim3((DH * DH + 255) / 256), 256, 0, stream>>>(W2, w2t, DH, DH);
  k_convT<<<dim3((DH * DOUT + 255) / 256), 256, 0, stream>>>(W3, w3t, DH, DOUT);

  // graph prep: degree count -> row_ptr scan -> norm -> two-level CSR build
  hipMemsetAsync(cnt, 0, (size_t)N * 4, stream);
  hipMemsetAsync(gfill, 0, (size_t)NBMAX * 4, stream);
  k_count<<<dim3((E + 255) / 256), 256, 0, stream>>>(dst, cnt, E);
  int nb = (N + 1023) / 1024;
  k_scan_block<<<dim3(nb), 256, 0, stream>>>(cnt, rp, bsum, N);
  k_scan_bsum<<<dim3(1), 256, 0, stream>>>(bsum, nb);
  k_scan_add<<<dim3((N + 255) / 256), 256, 0, stream>>>(rp, bsum, N, E);
  k_norm<<<dim3((N + 255) / 256), 256, 0, stream>>>(cnt, nrm, N);
  k_bucket_scatter<<<dim3((E + 4095) / 4096), 256, 0, stream>>>(src, dst, rp, gfill, tmp, E, nbuck, N);
  k_bucket_sort<<<dim3(nbuck), 256, 0, stream>>>(tmp, rp, ss, N);

  // MLP (bf16 MFMA, fp32 accum)
  dim3 g1((N + 127) / 128, DH / 128);
  k_gemm<128, 2, 2, true, true><<<g1, 256, 0, stream>>>(featsb, w1t, b1, x1b, N, DH);
  k_gemm<128, 2, 2, true, true><<<g1, 256, 0, stream>>>(x1b, w2t, b2, featsb, N, DH);
  dim3 g3((N + 127) / 128, 1);
  k_gemm<32, 4, 1, false, false><<<g3, 256, 0, stream>>>(featsb, w3t, b3, xout, N, DOUT);

  // pooling init + 16 hops
  k_init<<<dim3((N + 7) / 8), 256, 0, stream>>>(xout, hsA, nrm, svec, N);
  ushort* hin = hsA;
  ushort* hout = hsB;
  for (int h = 0; h < KHOP; ++h) {
    k_prop<<<dim3((N + 3) / 4), 256, 0, stream>>>(hin, hout, xout, rp, ss, nrm, svec, N);
    ushort* t = hin; hin = hout; hout = t;
  }
}